// Round 7
// baseline (613.563 us; speedup 1.0000x reference)
//
#include <hip/hip_runtime.h>
#include <hip/hip_fp16.h>
#include <math.h>

#define N_B 16
#define N_A 1024
#define N_D 1024
#define N_H 512
#define N_W 512

typedef _Float16 half2t __attribute__((ext_vector_type(2)));

__device__ inline half2t h2cast(unsigned u) {
    union { unsigned u; half2t h; } cv; cv.u = u; return cv.h;
}

__device__ inline float fdot2f(half2t a, half2t b, float c) {
#if __has_builtin(__builtin_amdgcn_fdot2)
    return __builtin_amdgcn_fdot2(a, b, c, false);
#else
    asm("v_dot2_f32_f16 %0, %1, %2, %0" : "+v"(c) : "v"(a), "v"(b));
    return c;
#endif
}

__device__ inline half2t pack_h2(float lo, float hi) {
#if __has_builtin(__builtin_amdgcn_cvt_pkrtz)
    auto r = __builtin_amdgcn_cvt_pkrtz(lo, hi);
    union { decltype(r) a; half2t h; } cv; cv.a = r; return cv.h;
#else
    half2t r; r.x = (_Float16)lo; r.y = (_Float16)hi; return r;
#endif
}

__device__ inline unsigned pack_u(float lo, float hi) {
    union { half2t h; unsigned u; } cv; cv.h = pack_h2(lo, hi); return cv.u;
}

__device__ inline float med3f(float a, float lo, float hi) {
#if __has_builtin(__builtin_amdgcn_fmed3f)
    return __builtin_amdgcn_fmed3f(a, lo, hi);
#else
    return fminf(fmaxf(a, lo), hi);
#endif
}

// ---------------------------------------------------------------------------
__global__ void fan_setup_kernel(const float* __restrict__ angles,
                                 float* __restrict__ twr,
                                 float* __restrict__ twi,
                                 float2* __restrict__ cs) {
    int t = blockIdx.x * 256 + threadIdx.x;
    if (t < 512) {
        double ang = -2.0 * M_PI * (double)t / 1024.0;
        twr[t] = (float)cos(ang);
        twi[t] = (float)sin(ang);
    }
    if (t < 1024) {
        double b = (double)angles[t];
        cs[t] = make_float2((float)cos(b), (float)sin(b));
    }
}

// ---------------------------------------------------------------------------
// FFT ramp filter, 4 batch-rows per block (one angle), as TWO packed complex
// FFTs. Output entry pf4[((g*1024+a)*1024)+d] (16B) = 4 batches' bilinear
// half2 pair (f[d], f[d+1]) so backprojection fetches with ONE dwordx4.
// ---------------------------------------------------------------------------
__global__ __launch_bounds__(256) void fan_fft_filter4_kernel(
    const float* __restrict__ sino, const float* __restrict__ filt,
    const float* __restrict__ twr_g, const float* __restrict__ twi_g,
    uint4* __restrict__ pf4) {
    __shared__ float s_re0[1024], s_im0[1024];
    __shared__ float s_re1[1024], s_im1[1024];
    __shared__ float s_twr[512], s_twi[512];

    const int tid = threadIdx.x;
    const int a = blockIdx.x & (N_A - 1);
    const int g = blockIdx.x >> 10;

    {
        float2 t0 = ((const float2*)twr_g)[tid];
        s_twr[2 * tid] = t0.x; s_twr[2 * tid + 1] = t0.y;
        float2 t1 = ((const float2*)twi_g)[tid];
        s_twi[2 * tid] = t1.x; s_twi[2 * tid + 1] = t1.y;
    }
    {
        const size_t rowstride = (size_t)N_A * N_D;
        const float* rb = sino + (size_t)(4 * g) * rowstride + (size_t)a * N_D;
        ((float4*)s_re0)[tid] = ((const float4*)(rb + 0 * rowstride))[tid];
        ((float4*)s_im0)[tid] = ((const float4*)(rb + 1 * rowstride))[tid];
        ((float4*)s_re1)[tid] = ((const float4*)(rb + 2 * rowstride))[tid];
        ((float4*)s_im1)[tid] = ((const float4*)(rb + 3 * rowstride))[tid];
    }
    __syncthreads();

    for (int L = 9; L >= 0; --L) {
        const int half = 1 << L;
#pragma unroll
        for (int q = 0; q < 4; ++q) {
            float* re = (q < 2) ? s_re0 : s_re1;
            float* im = (q < 2) ? s_im0 : s_im1;
            const int bf = tid + ((q & 1) << 8);
            const int j = bf & (half - 1);
            const int blk = bf >> L;
            const int base = (blk << (L + 1)) + j;
            const int tw = j << (9 - L);
            const float wr = s_twr[tw], wi = s_twi[tw];
            const float ar = re[base], ai = im[base];
            const float br = re[base + half], bi = im[base + half];
            re[base] = ar + br;
            im[base] = ai + bi;
            const float dr = ar - br, di = ai - bi;
            re[base + half] = dr * wr - di * wi;
            im[base + half] = dr * wi + di * wr;
        }
        __syncthreads();
    }

#pragma unroll
    for (int q = 0; q < 4; ++q) {
        const int i = tid + (q << 8);
        const int ri = (int)(__brev((unsigned)i) >> 22);
        const float f = filt[ri];
        s_re0[i] *= f; s_im0[i] *= f;
        s_re1[i] *= f; s_im1[i] *= f;
    }
    __syncthreads();

    for (int L = 0; L <= 9; ++L) {
        const int half = 1 << L;
#pragma unroll
        for (int q = 0; q < 4; ++q) {
            float* re = (q < 2) ? s_re0 : s_re1;
            float* im = (q < 2) ? s_im0 : s_im1;
            const int bf = tid + ((q & 1) << 8);
            const int j = bf & (half - 1);
            const int blk = bf >> L;
            const int base = (blk << (L + 1)) + j;
            const int tw = j << (9 - L);
            const float wr = s_twr[tw], wi = -s_twi[tw];
            const float ar = re[base], ai = im[base];
            const float tr = re[base + half], ti = im[base + half];
            const float br = tr * wr - ti * wi;
            const float bi = tr * wi + ti * wr;
            re[base] = ar + br;
            im[base] = ai + bi;
            re[base + half] = ar - br;
            im[base + half] = ai - bi;
        }
        __syncthreads();
    }

    const float invN = 1.0f / 1024.0f;
    uint4* dst = pf4 + ((size_t)g * N_A + (size_t)a) * N_D;
#pragma unroll
    for (int q = 0; q < 4; ++q) {
        const int n = tid + (q << 8);
        const int n1 = (n < 1023) ? n + 1 : n;
        const float e = (n < 1023) ? 1.0f : 0.0f;
        uint4 v;
        v.x = pack_u(s_re0[n] * invN, s_re0[n1] * invN * e);
        v.y = pack_u(s_im0[n] * invN, s_im0[n1] * invN * e);
        v.z = pack_u(s_re1[n] * invN, s_re1[n1] * invN * e);
        v.w = pack_u(s_im1[n] * invN, s_im1[n1] * invN * e);
        dst[n] = v;
    }
}

// ---------------------------------------------------------------------------
// Backprojection: 16x16 pixel tile per block; per ITERATION process an
// adjacent angle PAIR (a, a+1) as two independent streams: 2x geometry,
// 8 independent saddr dwordx4 gathers, 32 fdot2. Adjacent angles hit the
// same cache lines (window shift <~3 entries) -> 2x MLP at no L1 cost.
// ---------------------------------------------------------------------------
#define CONSUME(WP, V0, V1, V2, V3)                                           \
    {                                                                         \
        acc[0] = fdot2f(h2cast(V0.x), WP, acc[0]);                            \
        acc[1] = fdot2f(h2cast(V0.y), WP, acc[1]);                            \
        acc[2] = fdot2f(h2cast(V0.z), WP, acc[2]);                            \
        acc[3] = fdot2f(h2cast(V0.w), WP, acc[3]);                            \
        acc[4] = fdot2f(h2cast(V1.x), WP, acc[4]);                            \
        acc[5] = fdot2f(h2cast(V1.y), WP, acc[5]);                            \
        acc[6] = fdot2f(h2cast(V1.z), WP, acc[6]);                            \
        acc[7] = fdot2f(h2cast(V1.w), WP, acc[7]);                            \
        acc[8] = fdot2f(h2cast(V2.x), WP, acc[8]);                            \
        acc[9] = fdot2f(h2cast(V2.y), WP, acc[9]);                            \
        acc[10] = fdot2f(h2cast(V2.z), WP, acc[10]);                          \
        acc[11] = fdot2f(h2cast(V2.w), WP, acc[11]);                          \
        acc[12] = fdot2f(h2cast(V3.x), WP, acc[12]);                          \
        acc[13] = fdot2f(h2cast(V3.y), WP, acc[13]);                          \
        acc[14] = fdot2f(h2cast(V3.z), WP, acc[14]);                          \
        acc[15] = fdot2f(h2cast(V3.w), WP, acc[15]);                          \
    }

template <int SPLIT>
__global__ __launch_bounds__(256) void fan_backproject_kernel(
    const uint4* __restrict__ pf4, const float2* __restrict__ cs_g,
    float* __restrict__ dst0, float* __restrict__ dst1) {
    __shared__ float2 lcs[N_A];
    const int tid = threadIdx.x;
#pragma unroll
    for (int q = 0; q < 4; ++q) {
        const int a = tid + (q << 8);
        lcs[a] = cs_g[a];
    }
    __syncthreads();

    // XCD-chunked bijective swizzle (gridDim.x % 8 == 0)
    const unsigned nwg = gridDim.x;
    const unsigned swz = (blockIdx.x & 7) * (nwg >> 3) + (blockIdx.x >> 3);
    const int part = (SPLIT >= 2) ? (int)(swz >> 10) : 0;
    const int tb = (SPLIT >= 2) ? (int)(swz & 1023) : (int)swz;
    const int ACNT = N_A / SPLIT;
    const int abase = part * ACNT;

    // 16x16 tile: 32x32 grid of tiles
    const int tile_x = tb & 31;
    const int tile_y = tb >> 5;
    const int tx = tid & 15;
    const int ty = tid >> 4;
    const int xi = tile_x * 16 + tx;
    const int yi = tile_y * 16 + ty;
    const float x = ((float)xi - 255.5f);  // VX = 1.0
    const float y = ((float)yi - 255.5f);

    // uniform per-group bases -> SGPR pairs; 32-bit element index -> saddr
    const uint4* __restrict__ g0 = pf4;
    const uint4* __restrict__ g1 = pf4 + ((size_t)1 << 20);
    const uint4* __restrict__ g2 = pf4 + ((size_t)2 << 20);
    const uint4* __restrict__ g3 = pf4 + ((size_t)3 << 20);

    float acc[N_B];
#pragma unroll
    for (int b = 0; b < N_B; ++b) acc[b] = 0.0f;

    auto geomload = [&](int a_, half2t& wp, uint4& V0, uint4& V1, uint4& V2,
                        uint4& V3) {
        const float2 csp = lcs[a_];
        const float c = csp.x, s = csp.y;
        const float t = fmaf(x, c, fmaf(y, s, 750.0f));  // D_SI + X c + Y s
        const float r = __builtin_amdgcn_rcpf(t);
        const float num = fmaf(y, c, -(x * s));
        const float idx = fmaf(num * r, 960.0f, 511.5f); // D_SD/DU = 960
        const float idxc = med3f(idx, 0.0f, 1023.0f);
        const float i0f = floorf(idxc);
        const float frac = idxc - i0f;
        const float wr = 750.0f * r;
        float wd = wr * wr;                              // (D_SI/t)^2
        wd = (idx == idxc) ? wd : 0.0f;
        const float w1 = wd * frac;
        const float w0 = wd - w1;
        wp = pack_h2(w0, w1);
        const unsigned off = ((unsigned)a_ << 10) + (unsigned)(int)i0f;
        V0 = g0[off];
        V1 = g1[off];
        V2 = g2[off];
        V3 = g3[off];
    };

    half2t wpA, wpB;
    uint4 A0, A1, A2, A3, B0, B1, B2, B3;

    for (int aa = 0; aa < ACNT; aa += 2) {
        geomload(abase + aa, wpA, A0, A1, A2, A3);
        geomload(abase + aa + 1, wpB, B0, B1, B2, B3);
        CONSUME(wpA, A0, A1, A2, A3);
        CONSUME(wpB, B0, B1, B2, B3);
    }

    const float scale = 3.14159265358979323846f / 1024.0f;  // pi / A
    float* dst = (SPLIT >= 2 && part == 1) ? dst1 : dst0;
    const size_t pix = (size_t)yi * N_W + (size_t)xi;
#pragma unroll
    for (int b = 0; b < N_B; ++b) {
        dst[(size_t)b * (N_H * N_W) + pix] = acc[b] * scale;
    }
}

// ---------------------------------------------------------------------------
__global__ __launch_bounds__(256) void fan_reduce_kernel(
    const float4* __restrict__ a, const float4* __restrict__ b,
    float4* __restrict__ o) {
    const int i = blockIdx.x * 256 + threadIdx.x;
    const float4 va = a[i], vb = b[i];
    o[i] = make_float4(va.x + vb.x, va.y + vb.y, va.z + vb.z, va.w + vb.w);
}

// ---------------------------------------------------------------------------
extern "C" void kernel_launch(void* const* d_in, const int* in_sizes, int n_in,
                              void* d_out, int out_size, void* d_ws, size_t ws_size,
                              hipStream_t stream) {
    const float* sino = (const float*)d_in[0];    // [16, 1024, 1024] f32
    const float* filt = (const float*)d_in[1];    // [1024] f32
    const float* angles = (const float*)d_in[2];  // [1024] f32
    float* out = (float*)d_out;                   // [16, 512, 512] f32

    float* twr = (float*)d_ws;
    float* twi = twr + 512;
    float2* cs = (float2*)(twi + 512);
    char* base = (char*)d_ws;
    uint4* pf4 = (uint4*)(base + 16384);
    const size_t PF_BYTES = (size_t)4 * N_A * N_D * 16;  // 64 MB
    float* partial0 = (float*)(base + 16384 + PF_BYTES);
    float* partial1 = partial0 + (size_t)N_B * N_H * N_W;
    const size_t need = 16384 + PF_BYTES + 2 * (size_t)N_B * N_H * N_W * 4;

    fan_setup_kernel<<<4, 256, 0, stream>>>(angles, twr, twi, cs);
    fan_fft_filter4_kernel<<<4 * N_A, 256, 0, stream>>>(sino, filt, twr, twi,
                                                        pf4);
    if (ws_size >= need) {
        fan_backproject_kernel<2><<<(N_H * N_W) / 256 * 2, 256, 0, stream>>>(
            pf4, cs, partial0, partial1);
        fan_reduce_kernel<<<(N_B * N_H * N_W) / 4 / 256, 256, 0, stream>>>(
            (const float4*)partial0, (const float4*)partial1, (float4*)out);
    } else {
        fan_backproject_kernel<1><<<(N_H * N_W) / 256, 256, 0, stream>>>(
            pf4, cs, out, out);
    }
}

// Round 8
// 557.319 us; speedup vs baseline: 1.1009x; 1.1009x over previous
//
#include <hip/hip_runtime.h>
#include <hip/hip_fp16.h>
#include <math.h>

#define N_B 16
#define N_A 1024
#define N_D 1024
#define N_H 512
#define N_W 512

typedef _Float16 half2t __attribute__((ext_vector_type(2)));
typedef unsigned uint4v __attribute__((ext_vector_type(4)));

__device__ inline half2t h2cast(unsigned u) {
    union { unsigned u; half2t h; } cv; cv.u = u; return cv.h;
}

__device__ inline float fdot2f(half2t a, half2t b, float c) {
#if __has_builtin(__builtin_amdgcn_fdot2)
    return __builtin_amdgcn_fdot2(a, b, c, false);
#else
    asm("v_dot2_f32_f16 %0, %1, %2, %0" : "+v"(c) : "v"(a), "v"(b));
    return c;
#endif
}

__device__ inline half2t pack_h2(float lo, float hi) {
#if __has_builtin(__builtin_amdgcn_cvt_pkrtz)
    auto r = __builtin_amdgcn_cvt_pkrtz(lo, hi);
    union { decltype(r) a; half2t h; } cv; cv.a = r; return cv.h;
#else
    half2t r; r.x = (_Float16)lo; r.y = (_Float16)hi; return r;
#endif
}

__device__ inline unsigned pack_u(float lo, float hi) {
    union { half2t h; unsigned u; } cv; cv.h = pack_h2(lo, hi); return cv.u;
}

__device__ inline float med3f(float a, float lo, float hi) {
#if __has_builtin(__builtin_amdgcn_fmed3f)
    return __builtin_amdgcn_fmed3f(a, lo, hi);
#else
    return fminf(fmaxf(a, lo), hi);
#endif
}

// ---------------------------------------------------------------------------
__global__ void fan_setup_kernel(const float* __restrict__ angles,
                                 float* __restrict__ twr,
                                 float* __restrict__ twi,
                                 float2* __restrict__ cs) {
    int t = blockIdx.x * 256 + threadIdx.x;
    if (t < 512) {
        double ang = -2.0 * M_PI * (double)t / 1024.0;
        twr[t] = (float)cos(ang);
        twi[t] = (float)sin(ang);
    }
    if (t < 1024) {
        double b = (double)angles[t];
        cs[t] = make_float2((float)cos(b), (float)sin(b));
    }
}

// ---------------------------------------------------------------------------
// FFT ramp filter, 4 batch-rows per block (one angle), as TWO packed complex
// FFTs. Output entry pf4[((g*1024+a)*1024)+d] (16B) = 4 batches' bilinear
// half2 pair (f[d], f[d+1]) so backprojection fetches with ONE dwordx4.
// ---------------------------------------------------------------------------
__global__ __launch_bounds__(256) void fan_fft_filter4_kernel(
    const float* __restrict__ sino, const float* __restrict__ filt,
    const float* __restrict__ twr_g, const float* __restrict__ twi_g,
    uint4* __restrict__ pf4) {
    __shared__ float s_re0[1024], s_im0[1024];
    __shared__ float s_re1[1024], s_im1[1024];
    __shared__ float s_twr[512], s_twi[512];

    const int tid = threadIdx.x;
    const int a = blockIdx.x & (N_A - 1);
    const int g = blockIdx.x >> 10;

    {
        float2 t0 = ((const float2*)twr_g)[tid];
        s_twr[2 * tid] = t0.x; s_twr[2 * tid + 1] = t0.y;
        float2 t1 = ((const float2*)twi_g)[tid];
        s_twi[2 * tid] = t1.x; s_twi[2 * tid + 1] = t1.y;
    }
    {
        const size_t rowstride = (size_t)N_A * N_D;
        const float* rb = sino + (size_t)(4 * g) * rowstride + (size_t)a * N_D;
        ((float4*)s_re0)[tid] = ((const float4*)(rb + 0 * rowstride))[tid];
        ((float4*)s_im0)[tid] = ((const float4*)(rb + 1 * rowstride))[tid];
        ((float4*)s_re1)[tid] = ((const float4*)(rb + 2 * rowstride))[tid];
        ((float4*)s_im1)[tid] = ((const float4*)(rb + 3 * rowstride))[tid];
    }
    __syncthreads();

    for (int L = 9; L >= 0; --L) {
        const int half = 1 << L;
#pragma unroll
        for (int q = 0; q < 4; ++q) {
            float* re = (q < 2) ? s_re0 : s_re1;
            float* im = (q < 2) ? s_im0 : s_im1;
            const int bf = tid + ((q & 1) << 8);
            const int j = bf & (half - 1);
            const int blk = bf >> L;
            const int base = (blk << (L + 1)) + j;
            const int tw = j << (9 - L);
            const float wr = s_twr[tw], wi = s_twi[tw];
            const float ar = re[base], ai = im[base];
            const float br = re[base + half], bi = im[base + half];
            re[base] = ar + br;
            im[base] = ai + bi;
            const float dr = ar - br, di = ai - bi;
            re[base + half] = dr * wr - di * wi;
            im[base + half] = dr * wi + di * wr;
        }
        __syncthreads();
    }

#pragma unroll
    for (int q = 0; q < 4; ++q) {
        const int i = tid + (q << 8);
        const int ri = (int)(__brev((unsigned)i) >> 22);
        const float f = filt[ri];
        s_re0[i] *= f; s_im0[i] *= f;
        s_re1[i] *= f; s_im1[i] *= f;
    }
    __syncthreads();

    for (int L = 0; L <= 9; ++L) {
        const int half = 1 << L;
#pragma unroll
        for (int q = 0; q < 4; ++q) {
            float* re = (q < 2) ? s_re0 : s_re1;
            float* im = (q < 2) ? s_im0 : s_im1;
            const int bf = tid + ((q & 1) << 8);
            const int j = bf & (half - 1);
            const int blk = bf >> L;
            const int base = (blk << (L + 1)) + j;
            const int tw = j << (9 - L);
            const float wr = s_twr[tw], wi = -s_twi[tw];
            const float ar = re[base], ai = im[base];
            const float tr = re[base + half], ti = im[base + half];
            const float br = tr * wr - ti * wi;
            const float bi = tr * wi + ti * wr;
            re[base] = ar + br;
            im[base] = ai + bi;
            re[base + half] = ar - br;
            im[base + half] = ai - bi;
        }
        __syncthreads();
    }

    const float invN = 1.0f / 1024.0f;
    uint4* dst = pf4 + ((size_t)g * N_A + (size_t)a) * N_D;
#pragma unroll
    for (int q = 0; q < 4; ++q) {
        const int n = tid + (q << 8);
        const int n1 = (n < 1023) ? n + 1 : n;
        const float e = (n < 1023) ? 1.0f : 0.0f;
        uint4 v;
        v.x = pack_u(s_re0[n] * invN, s_re0[n1] * invN * e);
        v.y = pack_u(s_im0[n] * invN, s_im0[n1] * invN * e);
        v.z = pack_u(s_re1[n] * invN, s_re1[n1] * invN * e);
        v.w = pack_u(s_im1[n] * invN, s_im1[n1] * invN * e);
        dst[n] = v;
    }
}

// ---------------------------------------------------------------------------
// Backprojection: 16x16 pixel tile per block. Inline-asm saddr gathers
// (global_load_dwordx4 vdst, voff, s[base]) with counted s_waitcnt vmcnt(8):
// a forced 2-deep pipeline (16 loads in flight) the compiler cannot sink.
// ---------------------------------------------------------------------------
#define GEOM(A_, WP0_, WP1_, OFF_)                                            \
    {                                                                         \
        const int a_ = (A_);                                                  \
        const float2 csp = lcs[a_];                                          \
        const float c = csp.x, s = csp.y;                                    \
        const float t = fmaf(x, c, fmaf(y, s, 750.0f));                      \
        const float r = __builtin_amdgcn_rcpf(t);                            \
        const float num = fmaf(y, c, -(x * s));                              \
        const float idx = fmaf(num * r, 960.0f, 511.5f);                     \
        const float idxc = med3f(idx, 0.0f, 1023.0f);                        \
        const float i0f = floorf(idxc);                                      \
        const float frac = idxc - i0f;                                       \
        const float wr_ = 750.0f * r;                                        \
        float wd = wr_ * wr_;                                                \
        wd = (idx == idxc) ? wd : 0.0f;                                      \
        const float w1 = wd * frac;                                          \
        const float w0 = wd - w1;                                            \
        WP0_ = w0; WP1_ = w1;                                                \
        OFF_ = (((unsigned)a_ << 10) + (unsigned)(int)i0f) << 4;             \
    }

// 4 loads, one shared 32-bit byte voffset, 4 SGPR-pair bases. Early-clobber.
#define ISSUE4(V0_, V1_, V2_, V3_, OFF_)                                      \
    asm volatile(                                                             \
        "global_load_dwordx4 %0, %4, %5\n\t"                                  \
        "global_load_dwordx4 %1, %4, %6\n\t"                                  \
        "global_load_dwordx4 %2, %4, %7\n\t"                                  \
        "global_load_dwordx4 %3, %4, %8"                                      \
        : "=&v"(V0_), "=&v"(V1_), "=&v"(V2_), "=&v"(V3_)                      \
        : "v"(OFF_), "s"(g0), "s"(g1), "s"(g2), "s"(g3));

#define VMWAIT(N_)                                                            \
    {                                                                         \
        asm volatile("s_waitcnt vmcnt(" #N_ ")" ::: "memory");                \
        __builtin_amdgcn_sched_barrier(0);                                    \
    }

#define CONSUME1(WP_, V0_, V1_, V2_, V3_)                                     \
    {                                                                         \
        acc[0] = fdot2f(h2cast(V0_[0]), WP_, acc[0]);                         \
        acc[1] = fdot2f(h2cast(V0_[1]), WP_, acc[1]);                         \
        acc[2] = fdot2f(h2cast(V0_[2]), WP_, acc[2]);                         \
        acc[3] = fdot2f(h2cast(V0_[3]), WP_, acc[3]);                         \
        acc[4] = fdot2f(h2cast(V1_[0]), WP_, acc[4]);                         \
        acc[5] = fdot2f(h2cast(V1_[1]), WP_, acc[5]);                         \
        acc[6] = fdot2f(h2cast(V1_[2]), WP_, acc[6]);                         \
        acc[7] = fdot2f(h2cast(V1_[3]), WP_, acc[7]);                         \
        acc[8] = fdot2f(h2cast(V2_[0]), WP_, acc[8]);                         \
        acc[9] = fdot2f(h2cast(V2_[1]), WP_, acc[9]);                         \
        acc[10] = fdot2f(h2cast(V2_[2]), WP_, acc[10]);                       \
        acc[11] = fdot2f(h2cast(V2_[3]), WP_, acc[11]);                       \
        acc[12] = fdot2f(h2cast(V3_[0]), WP_, acc[12]);                       \
        acc[13] = fdot2f(h2cast(V3_[1]), WP_, acc[13]);                       \
        acc[14] = fdot2f(h2cast(V3_[2]), WP_, acc[14]);                       \
        acc[15] = fdot2f(h2cast(V3_[3]), WP_, acc[15]);                       \
    }

// Issue both angles of pair AA into bank X (weights wX*, regs X*)
#define ISSUE_PAIR(X, AA)                                                     \
    {                                                                         \
        float w0a, w1a, w0b, w1b;                                             \
        unsigned offa, offb;                                                  \
        GEOM((AA), w0a, w1a, offa);                                           \
        GEOM((AA) + 1, w0b, w1b, offb);                                       \
        wp##X##0 = pack_h2(w0a, w1a);                                         \
        wp##X##1 = pack_h2(w0b, w1b);                                         \
        ISSUE4(X##a0, X##a1, X##a2, X##a3, offa);                             \
        ISSUE4(X##b0, X##b1, X##b2, X##b3, offb);                             \
    }

#define CONSUME_PAIR(X)                                                       \
    {                                                                         \
        CONSUME1(wp##X##0, X##a0, X##a1, X##a2, X##a3);                       \
        CONSUME1(wp##X##1, X##b0, X##b1, X##b2, X##b3);                       \
    }

// body: issue pair AA into bank T, wait for previous pair, consume bank S
#define BODY(T, S, AA)                                                        \
    {                                                                         \
        ISSUE_PAIR(T, (AA));                                                  \
        VMWAIT(8);                                                            \
        CONSUME_PAIR(S);                                                      \
    }

template <int SPLIT>
__global__ __launch_bounds__(256) void fan_backproject_kernel(
    const uint4* __restrict__ pf4, const float2* __restrict__ cs_g,
    float* __restrict__ dst0, float* __restrict__ dst1) {
    __shared__ float2 lcs[N_A];
    const int tid = threadIdx.x;
#pragma unroll
    for (int q = 0; q < 4; ++q) {
        const int a = tid + (q << 8);
        lcs[a] = cs_g[a];
    }
    __syncthreads();

    // XCD-chunked bijective swizzle (gridDim.x % 8 == 0)
    const unsigned nwg = gridDim.x;
    const unsigned swz = (blockIdx.x & 7) * (nwg >> 3) + (blockIdx.x >> 3);
    const int part = (SPLIT >= 2) ? (int)(swz >> 10) : 0;
    const int tb = (SPLIT >= 2) ? (int)(swz & 1023) : (int)swz;
    const int ACNT = N_A / SPLIT;
    const int abase = part * ACNT;

    // 16x16 tile: 32x32 grid of tiles
    const int tile_x = tb & 31;
    const int tile_y = tb >> 5;
    const int tx = tid & 15;
    const int ty = tid >> 4;
    const int xi = tile_x * 16 + tx;
    const int yi = tile_y * 16 + ty;
    const float x = ((float)xi - 255.5f);  // VX = 1.0
    const float y = ((float)yi - 255.5f);

    // uniform base pointers (SGPR pairs for the asm saddr form)
    const unsigned* g0 = (const unsigned*)pf4;
    const unsigned* g1 = g0 + ((size_t)1 << 22);  // +16 MB in dwords
    const unsigned* g2 = g0 + ((size_t)2 << 22);
    const unsigned* g3 = g0 + ((size_t)3 << 22);

    float acc[N_B];
#pragma unroll
    for (int b = 0; b < N_B; ++b) acc[b] = 0.0f;

    half2t wpA0, wpA1, wpB0, wpB1;
    uint4v Aa0, Aa1, Aa2, Aa3, Ab0, Ab1, Ab2, Ab3;
    uint4v Ba0, Ba1, Ba2, Ba3, Bb0, Bb1, Bb2, Bb3;

    // prologue: pair 0 into bank A
    ISSUE_PAIR(A, abase);
    int aa = abase + 2;
    // first body (odd count of remaining bodies)
    BODY(B, A, aa);
    aa += 2;
    // remaining bodies, 2 per loop iteration: ACNT/4 - 1 iterations
    for (int it = 0; it < (ACNT >> 2) - 1; ++it) {
        BODY(A, B, aa);
        aa += 2;
        BODY(B, A, aa);
        aa += 2;
    }
    // epilogue: last pair is in bank B
    VMWAIT(0);
    CONSUME_PAIR(B);

    const float scale = 3.14159265358979323846f / 1024.0f;  // pi / A
    float* dst = (SPLIT >= 2 && part == 1) ? dst1 : dst0;
    const size_t pix = (size_t)yi * N_W + (size_t)xi;
#pragma unroll
    for (int b = 0; b < N_B; ++b) {
        dst[(size_t)b * (N_H * N_W) + pix] = acc[b] * scale;
    }
}

// ---------------------------------------------------------------------------
__global__ __launch_bounds__(256) void fan_reduce_kernel(
    const float4* __restrict__ a, const float4* __restrict__ b,
    float4* __restrict__ o) {
    const int i = blockIdx.x * 256 + threadIdx.x;
    const float4 va = a[i], vb = b[i];
    o[i] = make_float4(va.x + vb.x, va.y + vb.y, va.z + vb.z, va.w + vb.w);
}

// ---------------------------------------------------------------------------
extern "C" void kernel_launch(void* const* d_in, const int* in_sizes, int n_in,
                              void* d_out, int out_size, void* d_ws, size_t ws_size,
                              hipStream_t stream) {
    const float* sino = (const float*)d_in[0];    // [16, 1024, 1024] f32
    const float* filt = (const float*)d_in[1];    // [1024] f32
    const float* angles = (const float*)d_in[2];  // [1024] f32
    float* out = (float*)d_out;                   // [16, 512, 512] f32

    float* twr = (float*)d_ws;
    float* twi = twr + 512;
    float2* cs = (float2*)(twi + 512);
    char* base = (char*)d_ws;
    uint4* pf4 = (uint4*)(base + 16384);
    const size_t PF_BYTES = (size_t)4 * N_A * N_D * 16;  // 64 MB
    float* partial0 = (float*)(base + 16384 + PF_BYTES);
    float* partial1 = partial0 + (size_t)N_B * N_H * N_W;
    const size_t need = 16384 + PF_BYTES + 2 * (size_t)N_B * N_H * N_W * 4;

    fan_setup_kernel<<<4, 256, 0, stream>>>(angles, twr, twi, cs);
    fan_fft_filter4_kernel<<<4 * N_A, 256, 0, stream>>>(sino, filt, twr, twi,
                                                        pf4);
    if (ws_size >= need) {
        fan_backproject_kernel<2><<<(N_H * N_W) / 256 * 2, 256, 0, stream>>>(
            pf4, cs, partial0, partial1);
        fan_reduce_kernel<<<(N_B * N_H * N_W) / 4 / 256, 256, 0, stream>>>(
            (const float4*)partial0, (const float4*)partial1, (float4*)out);
    } else {
        fan_backproject_kernel<1><<<(N_H * N_W) / 256, 256, 0, stream>>>(
            pf4, cs, out, out);
    }
}